// Round 7
// baseline (3273.980 us; speedup 1.0000x reference)
//
#include <hip/hip_runtime.h>

typedef float f32x4 __attribute__((ext_vector_type(4)));
typedef short s16x8 __attribute__((ext_vector_type(8)));

#define NT 32768      // tokens
#define NK 8192       // embeddings
#define ND 256        // dim
#define NSP 32        // column splits (NK/256)
#define NKT 24        // K-tiles: logical K=768, BK=32

// round-to-nearest-even fp32 -> bf16 bits
static __device__ __forceinline__ ushort f2bf(float f) {
  unsigned u = __float_as_uint(f);
  unsigned r = (u + 0x7FFFu + ((u >> 16) & 1u)) >> 16;
  return (ushort)r;
}

// ---------------- fp32 [rows][256] -> bf16 split [rows][512] = [hi(256) | lo(256)] ----
__global__ __launch_bounds__(256) void vq_cvt(const float* __restrict__ src,
                                              ushort* __restrict__ dst) {
  size_t idx = (size_t)blockIdx.x * 256 + threadIdx.x;
  size_t n = idx >> 6;
  int dq = (int)(idx & 63) * 4;
  float4 v = *reinterpret_cast<const float4*>(src + n * ND + dq);
  float f[4] = {v.x, v.y, v.z, v.w};
  ushort h[4], l[4];
#pragma unroll
  for (int t = 0; t < 4; ++t) {
    h[t] = f2bf(f[t]);
    float hf = __uint_as_float((unsigned)h[t] << 16);
    l[t] = f2bf(f[t] - hf);   // exact residual, then RN
  }
  *reinterpret_cast<ushort4*>(dst + n * 512 + dq) = make_ushort4(h[0], h[1], h[2], h[3]);
  *reinterpret_cast<ushort4*>(dst + n * 512 + 256 + dq) = make_ushort4(l[0], l[1], l[2], l[3]);
}

// ---------------- ||e_k||^2 (exact fp32) ----------------
__global__ __launch_bounds__(256) void vq_esq(const float* __restrict__ emb,
                                              float* __restrict__ esq) {
  int w = threadIdx.x >> 6, lane = threadIdx.x & 63;
  int k = blockIdx.x * 4 + w;
  const float4 e = *reinterpret_cast<const float4*>(emb + (size_t)k * ND + lane * 4);
  float s = e.x * e.x + e.y * e.y + e.z * e.z + e.w * e.w;
#pragma unroll
  for (int off = 32; off >= 1; off >>= 1) s += __shfl_down(s, off);
  if (lane == 0) esq[k] = s;
}

#define GL16(gp, lp)                                                              \
  __builtin_amdgcn_global_load_lds(                                               \
      (const __attribute__((address_space(1))) unsigned int*)(gp),                \
      (__attribute__((address_space(3))) unsigned int*)(lp), 16, 0, 0)

#define BAR()                                                                     \
  do {                                                                            \
    asm volatile("" ::: "memory");                                                \
    __builtin_amdgcn_s_barrier();                                                 \
    asm volatile("" ::: "memory");                                                \
  } while (0)

// K-tile (BK=32) -> element offset in the [hi(256)|lo(256)] layout.
// terms: 0: z_hi.e_hi (kt 0-7), 1: z_hi.e_lo (kt 8-15), 2: z_lo.e_hi (kt 16-23)
__device__ __forceinline__ int koffA(int kt) { return ((kt >= 16) ? 256 : 0) + (kt & 7) * 32; }
__device__ __forceinline__ int koffB(int kt) { return ((kt >= 8 && kt < 16) ? 256 : 0) + (kt & 7) * 32; }

// ---------------- 256x256 tile, BK=32, 64KB LDS -> 2 blocks/CU + per-tile argmin ------------
// Cross-block overlap (m114): two independent blocks per CU breathe out of phase, so one
// block's MFMA cluster hides the other's stage/drain/barrier. dist = esq[k] - 2*cross.
__global__ __launch_bounds__(512, 4) void vq_mfma(
    const ushort* __restrict__ z2, const ushort* __restrict__ e2,
    const float* __restrict__ esq, float* __restrict__ pdist,
    int* __restrict__ pidx) {
  // A: [0,32K)   = [buf][256 rows][4 slots x 16B] bf16, slot-swizzled:
  //   phys slot p of row r holds logical k-slot p ^ ((r>>1)&3)
  // B: [32K,64K) same layout
  __shared__ __align__(16) char smem[65536];
  char* ldsA = smem;
  char* ldsB = smem + 32768;

  // XCD-aware 8x8 supertile swizzle: each XCD owns 8 supertiles (2MB A + 2MB B panels fit 4MiB L2)
  const int gid = blockIdx.x;
  const int x = gid & 7, c = gid >> 3;        // 512 blocks per XCD
  const int S = x * 8 + (c >> 6);             // global supertile 0..63
  const int wi = c & 63;
  const int mt = (S >> 2) * 8 + (wi >> 3);    // 0..127
  const int nt = (S & 3) * 8 + (wi & 7);      // 0..31
  const int m0 = mt * 256, n0 = nt * 256;

  const int tid = threadIdx.x, lane = tid & 63, wid = tid >> 6;
  const int wr = wid >> 2, wc = wid & 3;      // 2 x 4 waves, per-wave 128x64 output
  const int fr = lane & 15, g = lane >> 4;

  // staging: thread t covers row (t>>2), phys 16B slot (t&3); fetch the logical
  // slot that belongs there: sslot = (t&3) ^ ((row>>1)&3) = (t&3) ^ ((t>>3)&3)
  const int sslot = (tid & 3) ^ ((tid >> 3) & 3);
  const ushort* aBase = z2 + (size_t)(m0 + (tid >> 2)) * 512 + sslot * 8;
  const ushort* bBase = e2 + (size_t)(n0 + (tid >> 2)) * 512 + sslot * 8;

  // per kt: 16KB A + 16KB B; 2 GL16 lines each (rows t>>2 and t>>2+128)
#define STAGE_A(kt)                                                               \
  do {                                                                            \
    const ushort* _g = aBase + koffA(kt);                                         \
    char* _l = ldsA + (((kt) & 1) << 14) + tid * 16;                              \
    GL16(_g, _l);  GL16(_g + 65536, _l + 8192);                                   \
  } while (0)
#define STAGE_B(kt)                                                               \
  do {                                                                            \
    const ushort* _g = bBase + koffB(kt);                                         \
    char* _l = ldsB + (((kt) & 1) << 14) + tid * 16;                              \
    GL16(_g, _l);  GL16(_g + 65536, _l + 8192);                                   \
  } while (0)

  // fragment-read bases: row*64 + swizzled-slot*16
  const int lbyte = fr * 64 + (((g ^ (fr >> 1)) & 3) << 4);
  const int aro = wr * 8192 + lbyte;
  const int bro = wc * 4096 + lbyte;

  f32x4 acc[8][4];
  const f32x4 zero = {0.f, 0.f, 0.f, 0.f};
#pragma unroll
  for (int i = 0; i < 8; ++i)
#pragma unroll
    for (int j = 0; j < 4; ++j) acc[i][j] = zero;

  // prologue: stage kt0 into buf0, drain, barrier
  STAGE_A(0); STAGE_B(0);
  asm volatile("s_waitcnt vmcnt(0)" ::: "memory");
  BAR();

  // main loop: one barrier per K-tile. Hazards: kt stages buf^1 (readers kt-1, drained
  // at kt-1's lgkm0+barrier); kt reads buf (staged kt-1, vmcnt(0) before same barrier).
  // Stage issues at the TOP (~1500 cyc before its drain) -> end-of-tile vmcnt(0) ~free.
#pragma unroll 2
  for (int kt = 0; kt < NKT; ++kt) {
    const int bufo = (kt & 1) << 14;
    const char* pa = ldsA + bufo + aro;
    const char* pb = ldsB + bufo + bro;

    if (kt + 1 < NKT) { STAGE_A(kt + 1); STAGE_B(kt + 1); }

    s16x8 a0[4], a1[4], b[4];
#pragma unroll
    for (int j = 0; j < 4; ++j) b[j] = *(const s16x8*)(pb + j * 1024);
#pragma unroll
    for (int i = 0; i < 4; ++i) a0[i] = *(const s16x8*)(pa + i * 1024);
    __builtin_amdgcn_s_setprio(1);
#pragma unroll
    for (int i = 0; i < 4; ++i)
#pragma unroll
      for (int j = 0; j < 4; ++j)
        acc[i][j] = __builtin_amdgcn_mfma_f32_16x16x32_bf16(a0[i], b[j], acc[i][j], 0, 0, 0);
#pragma unroll
    for (int i = 0; i < 4; ++i) a1[i] = *(const s16x8*)(pa + (4 + i) * 1024);
#pragma unroll
    for (int i = 0; i < 4; ++i)
#pragma unroll
      for (int j = 0; j < 4; ++j)
        acc[4 + i][j] = __builtin_amdgcn_mfma_f32_16x16x32_bf16(a1[i], b[j], acc[4 + i][j], 0, 0, 0);
    __builtin_amdgcn_s_setprio(0);

    asm volatile("s_waitcnt vmcnt(0) lgkmcnt(0)" ::: "memory");
    __builtin_amdgcn_sched_barrier(0);
    BAR();
  }

  // ---- epilogue: per-row argmin over this block's 256 cols (shuffle butterfly) ----
  // C/D layout (16x16): col = wc*64 + j*16 + fr, row = wr*128 + i*16 + g*4 + r
  float eqv[4];
#pragma unroll
  for (int j = 0; j < 4; ++j) eqv[j] = esq[n0 + wc * 64 + j * 16 + fr];

  float (*rdv)[4] = (float(*)[4])smem;            // [256][4]
  int (*rdi)[4] = (int(*)[4])(smem + 4096);       // [256][4]

#pragma unroll
  for (int i = 0; i < 8; ++i)
#pragma unroll
    for (int r = 0; r < 4; ++r) {
      float bv = 3.4e38f; int bc = 0;
#pragma unroll
      for (int j = 0; j < 4; ++j) {
        float dist = fmaf(-2.f, acc[i][j][r], eqv[j]);
        int cl = wc * 64 + j * 16 + fr;
        if (dist < bv) { bv = dist; bc = cl; }   // j ascending -> first-min kept
      }
      // butterfly over fr within the 16-lane group (same g => same row)
#pragma unroll
      for (int off = 1; off < 16; off <<= 1) {
        float ov = __shfl_xor(bv, off);
        int oc = __shfl_xor(bc, off);
        if (ov < bv || (ov == bv && oc < bc)) { bv = ov; bc = oc; }
      }
      int row = wr * 128 + i * 16 + g * 4 + r;
      if (fr == 0) { rdv[row][wc] = bv; rdi[row][wc] = bc; }
    }
  BAR();
  if (tid < 256) {
    float bv = rdv[tid][0]; int bc = rdi[tid][0];
#pragma unroll
    for (int w = 1; w < 4; ++w) {
      float v = rdv[tid][w]; int cc = rdi[tid][w];
      if (v < bv || (v == bv && cc < bc)) { bv = v; bc = cc; }  // wc ascending = col ascending
    }
    int n = m0 + tid;
    pdist[(size_t)n * NSP + nt] = bv;
    pidx[(size_t)n * NSP + nt] = n0 + bc;
  }
}

// ---------------- merge partials, gather z_q, loss partials ----------------
__global__ __launch_bounds__(256) void vq_gather(
    const float* __restrict__ z, const float* __restrict__ emb,
    const float* __restrict__ pdist, const int* __restrict__ pidx,
    float* __restrict__ out, float* __restrict__ lpart) {
  int w = threadIdx.x >> 6, lane = threadIdx.x & 63;
  int n = blockIdx.x * 4 + w;
  int p = lane & (NSP - 1);
  float d = pdist[(size_t)n * NSP + p];
  int ii = pidx[(size_t)n * NSP + p];
#pragma unroll
  for (int off = 1; off < NSP; off <<= 1) {
    float od = __shfl_xor(d, off);
    int oi = __shfl_xor(ii, off);
    if (od < d || (od == d && oi < ii)) { d = od; ii = oi; }
  }
  int bi = ii;   // all lanes agree after butterfly (both 32-halves loaded same data)
  float4 q = *reinterpret_cast<const float4*>(emb + (size_t)bi * ND + lane * 4);
  float4 zz = *reinterpret_cast<const float4*>(z + (size_t)n * ND + lane * 4);
  *reinterpret_cast<float4*>(out + (size_t)n * ND + lane * 4) = q;  // z_q_st fwd == z_q
  float dx = zz.x - q.x, dy = zz.y - q.y, dz = zz.z - q.z, dw = zz.w - q.w;
  float s2 = dx * dx + dy * dy + dz * dz + dw * dw;
#pragma unroll
  for (int off = 32; off >= 1; off >>= 1) s2 += __shfl_down(s2, off);
  __shared__ float ls[4];
  if (lane == 0) {
    ls[w] = s2;
    out[(size_t)NT * ND + 1 + n] = (float)bi;  // indices as float
  }
  __syncthreads();
  if (threadIdx.x == 0) lpart[blockIdx.x] = ls[0] + ls[1] + ls[2] + ls[3];
}

// ---------------- deterministic loss finalize ----------------
__global__ __launch_bounds__(256) void vq_finalize(const float* __restrict__ lpart,
                                                   float* __restrict__ out) {
  __shared__ float s[256];
  float acc = 0.f;
  for (int i = threadIdx.x; i < NT / 4; i += 256) acc += lpart[i];
  s[threadIdx.x] = acc;
  __syncthreads();
  for (int st = 128; st >= 1; st >>= 1) {
    if (threadIdx.x < st) s[threadIdx.x] += s[threadIdx.x + st];
    __syncthreads();
  }
  if (threadIdx.x == 0)
    out[(size_t)NT * ND] = 1.25f * s[0] / (float)((size_t)NT * ND);
}

extern "C" void kernel_launch(void* const* d_in, const int* in_sizes, int n_in,
                              void* d_out, int out_size, void* d_ws, size_t ws_size,
                              hipStream_t stream) {
  const float* z = (const float*)d_in[0];    // (NT, ND) fp32
  const float* emb = (const float*)d_in[1];  // (NK, ND) fp32
  float* out = (float*)d_out;                // [z_q (NT*ND)] [loss (1)] [idx (NT)]

  float* esq = (float*)d_ws;                           // NK f32
  ushort* z2 = (ushort*)(esq + NK);                    // NT*512 bf16
  ushort* e2 = z2 + (size_t)NT * 512;                  // NK*512 bf16
  float* pdist = (float*)(e2 + (size_t)NK * 512);      // NT*NSP f32
  int* pidx = (int*)(pdist + (size_t)NT * NSP);        // NT*NSP i32
  float* lpart = (float*)(pidx + (size_t)NT * NSP);    // NT/4 f32

  vq_cvt<<<NT / 4, 256, 0, stream>>>(z, z2);
  vq_cvt<<<NK / 4, 256, 0, stream>>>(emb, e2);
  vq_esq<<<NK / 4, 256, 0, stream>>>(emb, esq);
  vq_mfma<<<4096, 512, 0, stream>>>(z2, e2, esq, pdist, pidx);
  vq_gather<<<NT / 4, 256, 0, stream>>>(z, emb, pdist, pidx, out, lpart);
  vq_finalize<<<1, 256, 0, stream>>>(lpart, out);
}

// Round 9
// 507.659 us; speedup vs baseline: 6.4492x; 6.4492x over previous
//
#include <hip/hip_runtime.h>

typedef float f32x4 __attribute__((ext_vector_type(4)));
typedef short s16x8 __attribute__((ext_vector_type(8)));

#define NT 32768      // tokens
#define NK 8192       // embeddings
#define ND 256        // dim
#define NSP 64        // column splits (NK/128)
#define NKT 24        // K-tiles: logical K=768, BK=32

// round-to-nearest-even fp32 -> bf16 bits
static __device__ __forceinline__ ushort f2bf(float f) {
  unsigned u = __float_as_uint(f);
  unsigned r = (u + 0x7FFFu + ((u >> 16) & 1u)) >> 16;
  return (ushort)r;
}

// ---------------- fp32 [rows][256] -> bf16 split [rows][512] = [hi(256) | lo(256)] ----
__global__ __launch_bounds__(256) void vq_cvt(const float* __restrict__ src,
                                              ushort* __restrict__ dst) {
  size_t idx = (size_t)blockIdx.x * 256 + threadIdx.x;
  size_t n = idx >> 6;
  int dq = (int)(idx & 63) * 4;
  float4 v = *reinterpret_cast<const float4*>(src + n * ND + dq);
  float f[4] = {v.x, v.y, v.z, v.w};
  ushort h[4], l[4];
#pragma unroll
  for (int t = 0; t < 4; ++t) {
    h[t] = f2bf(f[t]);
    float hf = __uint_as_float((unsigned)h[t] << 16);
    l[t] = f2bf(f[t] - hf);   // exact residual, then RN
  }
  *reinterpret_cast<ushort4*>(dst + n * 512 + dq) = make_ushort4(h[0], h[1], h[2], h[3]);
  *reinterpret_cast<ushort4*>(dst + n * 512 + 256 + dq) = make_ushort4(l[0], l[1], l[2], l[3]);
}

// ---------------- ||e_k||^2 (exact fp32) ----------------
__global__ __launch_bounds__(256) void vq_esq(const float* __restrict__ emb,
                                              float* __restrict__ esq) {
  int w = threadIdx.x >> 6, lane = threadIdx.x & 63;
  int k = blockIdx.x * 4 + w;
  const float4 e = *reinterpret_cast<const float4*>(emb + (size_t)k * ND + lane * 4);
  float s = e.x * e.x + e.y * e.y + e.z * e.z + e.w * e.w;
#pragma unroll
  for (int off = 32; off >= 1; off >>= 1) s += __shfl_down(s, off);
  if (lane == 0) esq[k] = s;
}

#define GL16(gp, lp)                                                              \
  __builtin_amdgcn_global_load_lds(                                               \
      (const __attribute__((address_space(1))) unsigned int*)(gp),                \
      (__attribute__((address_space(3))) unsigned int*)(lp), 16, 0, 0)

#define BAR()                                                                     \
  do {                                                                            \
    asm volatile("" ::: "memory");                                                \
    __builtin_amdgcn_s_barrier();                                                 \
    asm volatile("" ::: "memory");                                                \
  } while (0)

// K-tile (BK=32) -> element offset in the [hi(256)|lo(256)] layout.
// terms: 0: z_hi.e_hi (kt 0-7), 1: z_hi.e_lo (kt 8-15), 2: z_lo.e_hi (kt 16-23)
__device__ __forceinline__ int koffA(int kt) { return ((kt >= 16) ? 256 : 0) + (kt & 7) * 32; }
__device__ __forceinline__ int koffB(int kt) { return ((kt >= 8 && kt < 16) ? 256 : 0) + (kt & 7) * 32; }

// ---------------- 256x128 tile, 8 waves (4x2 of 64x64), 16x16x32 MFMA ----------------
// 48KB LDS + ~110 VGPR/wave at __launch_bounds__(512,4) -> 2 independent blocks/CU
// (4 waves/SIMD from DIFFERENT barrier domains). One block's MFMA cluster runs while
// the other stages/drains (m114 cross-block overlap). dist = esq[k] - 2*cross.
__global__ __launch_bounds__(512, 4) void vq_mfma(
    const ushort* __restrict__ z2, const ushort* __restrict__ e2,
    const float* __restrict__ esq, float* __restrict__ pdist,
    int* __restrict__ pidx) {
  // A: [0,32K)   = [buf][256 rows][4 slots x 16B] bf16, slot-swizzled:
  //   phys slot p of row r holds logical k-slot p ^ ((r>>1)&3)
  // B: [32K,48K) = [buf][128 rows][4 slots x 16B], same swizzle
  __shared__ __align__(16) char smem[49152];
  char* ldsA = smem;
  char* ldsB = smem + 32768;

  // XCD-aware supertile swizzle (bijective): 8192 blocks -> mt 0..127, nt 0..63.
  // Same construction as the verified 256x256 map, range extended.
  const int gid = blockIdx.x;
  const int x = gid & 7, c = gid >> 3;        // 1024 blocks per XCD
  const int S = x * 16 + (c >> 6);            // global supertile 0..127 (8mt x 8nt each)
  const int wi = c & 63;
  const int mt = (S >> 3) * 8 + (wi >> 3);    // 0..127
  const int nt = (S & 7) * 8 + (wi & 7);      // 0..63
  const int m0 = mt * 256, n0 = nt * 128;

  const int tid = threadIdx.x, lane = tid & 63, wid = tid >> 6;
  const int wr = wid >> 1, wcn = wid & 1;     // 4 x 2 waves, per-wave 64x64 output
  const int fr = lane & 15, g = lane >> 4;

  // staging: thread t covers row (t>>2), phys 16B slot (t&3); fetch the logical
  // slot that belongs there: sslot = (t&3) ^ ((row>>1)&3) = (t&3) ^ ((t>>3)&3)
  const int sslot = (tid & 3) ^ ((tid >> 3) & 3);
  const ushort* aBase = z2 + (size_t)(m0 + (tid >> 2)) * 512 + sslot * 8;
  const ushort* bBase = e2 + (size_t)(n0 + (tid >> 2)) * 512 + sslot * 8;

  // per kt: A 16KB (2 GL16 lines of 128 rows — R7-verified), B 8KB (1 line)
#define STAGE_A(kt)                                                               \
  do {                                                                            \
    const ushort* _g = aBase + koffA(kt);                                         \
    char* _l = ldsA + (((kt) & 1) << 14) + tid * 16;                              \
    GL16(_g, _l);  GL16(_g + 65536, _l + 8192);                                   \
  } while (0)
#define STAGE_B(kt)                                                               \
  do {                                                                            \
    const ushort* _g = bBase + koffB(kt);                                         \
    char* _l = ldsB + (((kt) & 1) << 13) + tid * 16;                              \
    GL16(_g, _l);                                                                 \
  } while (0)

  // fragment-read bases: row*64 + swizzled-slot*16 (R3-verified formula)
  const int lbyte = fr * 64 + (((g ^ (fr >> 1)) & 3) << 4);
  const int aro = wr * 4096 + lbyte;
  const int bro = wcn * 4096 + lbyte;

  f32x4 acc[4][4];
  const f32x4 zero = {0.f, 0.f, 0.f, 0.f};
#pragma unroll
  for (int i = 0; i < 4; ++i)
#pragma unroll
    for (int j = 0; j < 4; ++j) acc[i][j] = zero;

  // prologue
  STAGE_A(0); STAGE_B(0);
  asm volatile("s_waitcnt vmcnt(0)" ::: "memory");
  BAR();

  // one barrier per kt; stage kt+1 at top (buf^1, readers drained at kt-1's end).
#pragma unroll 2
  for (int kt = 0; kt < NKT; ++kt) {
    const char* pa = ldsA + ((kt & 1) << 14) + aro;
    const char* pb = ldsB + ((kt & 1) << 13) + bro;

    if (kt + 1 < NKT) { STAGE_A(kt + 1); STAGE_B(kt + 1); }

    s16x8 a0[2], a1[2], b[4];
#pragma unroll
    for (int j = 0; j < 4; ++j) b[j] = *(const s16x8*)(pb + j * 1024);
#pragma unroll
    for (int i = 0; i < 2; ++i) a0[i] = *(const s16x8*)(pa + i * 1024);
    __builtin_amdgcn_s_setprio(1);
#pragma unroll
    for (int i = 0; i < 2; ++i)
#pragma unroll
      for (int j = 0; j < 4; ++j)
        acc[i][j] = __builtin_amdgcn_mfma_f32_16x16x32_bf16(a0[i], b[j], acc[i][j], 0, 0, 0);
#pragma unroll
    for (int i = 0; i < 2; ++i) a1[i] = *(const s16x8*)(pa + (2 + i) * 1024);
#pragma unroll
    for (int i = 0; i < 2; ++i)
#pragma unroll
      for (int j = 0; j < 4; ++j)
        acc[2 + i][j] = __builtin_amdgcn_mfma_f32_16x16x32_bf16(a1[i], b[j], acc[2 + i][j], 0, 0, 0);
    __builtin_amdgcn_s_setprio(0);

    asm volatile("s_waitcnt vmcnt(0) lgkmcnt(0)" ::: "memory");
    __builtin_amdgcn_sched_barrier(0);
    BAR();
  }

  // ---- epilogue: per-row argmin over this block's 128 cols (R6-verified pattern) ----
  // C/D layout (16x16): col = wcn*64 + j*16 + fr, row = wr*64 + i*16 + g*4 + r
  float eqv[4];
#pragma unroll
  for (int j = 0; j < 4; ++j) eqv[j] = esq[n0 + wcn * 64 + j * 16 + fr];

  float (*rdv)[2] = (float(*)[2])smem;            // [256][2]
  int (*rdi)[2] = (int(*)[2])(smem + 2048);       // [256][2]

#pragma unroll
  for (int i = 0; i < 4; ++i)
#pragma unroll
    for (int r = 0; r < 4; ++r) {
      float bv = 3.4e38f; int bc = 0;
#pragma unroll
      for (int j = 0; j < 4; ++j) {
        float dist = fmaf(-2.f, acc[i][j][r], eqv[j]);
        int cl = wcn * 64 + j * 16 + fr;
        if (dist < bv) { bv = dist; bc = cl; }   // j ascending -> first-min kept
      }
      // butterfly over fr within the 16-lane group (same g => same row)
#pragma unroll
      for (int off = 1; off < 16; off <<= 1) {
        float ov = __shfl_xor(bv, off);
        int oc = __shfl_xor(bc, off);
        if (ov < bv || (ov == bv && oc < bc)) { bv = ov; bc = oc; }
      }
      int row = wr * 64 + i * 16 + g * 4 + r;
      if (fr == 0) { rdv[row][wcn] = bv; rdi[row][wcn] = bc; }
    }
  asm volatile("s_waitcnt lgkmcnt(0)" ::: "memory");   // drain ds_writes before barrier
  BAR();
  if (tid < 256) {
    float bv = rdv[tid][0]; int bc = rdi[tid][0];
    float v1 = rdv[tid][1]; int c1 = rdi[tid][1];
    if (v1 < bv || (v1 == bv && c1 < bc)) { bv = v1; bc = c1; }  // wcn ascending = col ascending
    int n = m0 + tid;
    pdist[(size_t)n * NSP + nt] = bv;
    pidx[(size_t)n * NSP + nt] = n0 + bc;
  }
}

// ---------------- merge partials, gather z_q, loss partials (round-0-verified) ----------------
__global__ __launch_bounds__(256) void vq_gather(
    const float* __restrict__ z, const float* __restrict__ emb,
    const float* __restrict__ pdist, const int* __restrict__ pidx,
    float* __restrict__ out, float* __restrict__ lpart) {
  int w = threadIdx.x >> 6, lane = threadIdx.x & 63;
  int n = blockIdx.x * 4 + w;
  float d = pdist[(size_t)n * NSP + lane];
  int ii = pidx[(size_t)n * NSP + lane];
#pragma unroll
  for (int off = 1; off < 64; off <<= 1) {
    float od = __shfl_xor(d, off);
    int oi = __shfl_xor(ii, off);
    if (od < d || (od == d && oi < ii)) { d = od; ii = oi; }
  }
  int bi = ii;   // all lanes agree after butterfly
  float4 q = *reinterpret_cast<const float4*>(emb + (size_t)bi * ND + lane * 4);
  float4 zz = *reinterpret_cast<const float4*>(z + (size_t)n * ND + lane * 4);
  *reinterpret_cast<float4*>(out + (size_t)n * ND + lane * 4) = q;  // z_q_st fwd == z_q
  float dx = zz.x - q.x, dy = zz.y - q.y, dz = zz.z - q.z, dw = zz.w - q.w;
  float s2 = dx * dx + dy * dy + dz * dz + dw * dw;
#pragma unroll
  for (int off = 32; off >= 1; off >>= 1) s2 += __shfl_down(s2, off);
  __shared__ float ls[4];
  if (lane == 0) {
    ls[w] = s2;
    out[(size_t)NT * ND + 1 + n] = (float)bi;  // indices as float
  }
  __syncthreads();
  if (threadIdx.x == 0) lpart[blockIdx.x] = ls[0] + ls[1] + ls[2] + ls[3];
}

// ---------------- deterministic loss finalize ----------------
__global__ __launch_bounds__(256) void vq_finalize(const float* __restrict__ lpart,
                                                   float* __restrict__ out) {
  __shared__ float s[256];
  float acc = 0.f;
  for (int i = threadIdx.x; i < NT / 4; i += 256) acc += lpart[i];
  s[threadIdx.x] = acc;
  __syncthreads();
  for (int st = 128; st >= 1; st >>= 1) {
    if (threadIdx.x < st) s[threadIdx.x] += s[threadIdx.x + st];
    __syncthreads();
  }
  if (threadIdx.x == 0)
    out[(size_t)NT * ND] = 1.25f * s[0] / (float)((size_t)NT * ND);
}

extern "C" void kernel_launch(void* const* d_in, const int* in_sizes, int n_in,
                              void* d_out, int out_size, void* d_ws, size_t ws_size,
                              hipStream_t stream) {
  const float* z = (const float*)d_in[0];    // (NT, ND) fp32
  const float* emb = (const float*)d_in[1];  // (NK, ND) fp32
  float* out = (float*)d_out;                // [z_q (NT*ND)] [loss (1)] [idx (NT)]

  float* esq = (float*)d_ws;                           // NK f32
  ushort* z2 = (ushort*)(esq + NK);                    // NT*512 bf16
  ushort* e2 = z2 + (size_t)NT * 512;                  // NK*512 bf16
  float* pdist = (float*)(e2 + (size_t)NK * 512);      // NT*NSP f32
  int* pidx = (int*)(pdist + (size_t)NT * NSP);        // NT*NSP i32
  float* lpart = (float*)(pidx + (size_t)NT * NSP);    // NT/4 f32

  vq_cvt<<<NT / 4, 256, 0, stream>>>(z, z2);
  vq_cvt<<<NK / 4, 256, 0, stream>>>(emb, e2);
  vq_esq<<<NK / 4, 256, 0, stream>>>(emb, esq);
  vq_mfma<<<8192, 512, 0, stream>>>(z2, e2, esq, pdist, pidx);
  vq_gather<<<NT / 4, 256, 0, stream>>>(z, emb, pdist, pidx, out, lpart);
  vq_finalize<<<1, 256, 0, stream>>>(lpart, out);
}